// Round 1
// baseline (627.904 us; speedup 1.0000x reference)
//
#include <hip/hip_runtime.h>
#include <math.h>

// Sizes (fixed): B=16, L=1024, D=50, V=129, d=64, N=2, H=8, DK=8, DFF=128, CVE=8
// LN eps = 1e-14, MASK_ATTN = -1e-30 (yes, ~zero), MASK_POOL = -1e30.

static __device__ __forceinline__ float wave_sum64(float x) {
#pragma unroll
    for (int off = 32; off > 0; off >>= 1) x += __shfl_xor(x, off, 64);
    return x;
}

// ---------------------------------------------------------------- embeddings
__global__ __launch_bounds__(256) void embed_kernel(
    const float* __restrict__ times, const float* __restrict__ values,
    const int* __restrict__ varis, const float* __restrict__ emb,
    const float* __restrict__ vW1, const float* __restrict__ vb1, const float* __restrict__ vW2,
    const float* __restrict__ tW1, const float* __restrict__ tb1, const float* __restrict__ tW2,
    float* __restrict__ X, float* __restrict__ mask)
{
    int row = blockIdx.x * 4 + (threadIdx.x >> 6);  // (b*L + l)
    int c   = threadIdx.x & 63;
    float v = values[row];
    float t = times[row];
    int var = varis[row];
    if (c == 0) mask[row] = (var > 0) ? 1.0f : 0.0f;
    float acc = emb[var * 64 + c];
#pragma unroll
    for (int j = 0; j < 8; ++j) {
        acc += tanhf(fmaf(v, vW1[j], vb1[j])) * vW2[j * 64 + c];
        acc += tanhf(fmaf(t, tW1[j], tb1[j])) * tW2[j * 64 + c];
    }
    X[row * 64 + c] = acc;
}

// ---------------------------------------------------------------- demo encoder
__global__ __launch_bounds__(128) void demo_kernel(
    const float* __restrict__ demo, const float* __restrict__ dW1, const float* __restrict__ db1,
    const float* __restrict__ dW2, const float* __restrict__ db2, float* __restrict__ denc)
{
    __shared__ float sh[128];
    int b = blockIdx.x;
    int t = threadIdx.x;
    float a = db1[t];
    for (int j = 0; j < 50; ++j) a = fmaf(demo[b * 50 + j], dW1[j * 128 + t], a);
    sh[t] = tanhf(a);
    __syncthreads();
    if (t < 64) {
        float a2 = db2[t];
#pragma unroll 8
        for (int j = 0; j < 128; ++j) a2 = fmaf(sh[j], dW2[j * 64 + t], a2);
        denc[b * 64 + t] = tanhf(a2);
    }
}

// ---------------------------------------------------------------- qkv projection
// X (16384 x 64) @ {Wq,Wk,Wv} (64x64 each, layout [h][c][kk]); out layout [(b*8+h)*1024+l]*8+kk
__global__ __launch_bounds__(256) void qkv_kernel(
    const float* __restrict__ X,
    const float* __restrict__ Wq, const float* __restrict__ Wk, const float* __restrict__ Wv,
    float* __restrict__ q, float* __restrict__ k, float* __restrict__ v)
{
    __shared__ float sWq[4096], sWk[4096], sWv[4096], sX[4096];
    int tid = threadIdx.x;
    // stage weights transposed: global [h][c][kk] -> lds [c][h*8+kk] (conflict-free reads)
    for (int idx = tid; idx < 4096; idx += 256) {
        int h = idx >> 9, c = (idx >> 3) & 63, kk = idx & 7;
        int l = c * 64 + h * 8 + kk;
        sWq[l] = Wq[idx];
        sWk[l] = Wk[idx];
        sWv[l] = Wv[idx];
    }
    int row0 = blockIdx.x * 64;
    for (int idx = tid; idx < 4096; idx += 256) sX[idx] = X[row0 * 64 + idx];
    __syncthreads();
    int lane = tid & 63;
    for (int iter = 0; iter < 16; ++iter) {
        int r = iter * 4 + (tid >> 6);
        float aq = 0.f, ak = 0.f, av = 0.f;
#pragma unroll 8
        for (int c = 0; c < 64; ++c) {
            float x = sX[r * 64 + c];
            aq = fmaf(x, sWq[c * 64 + lane], aq);
            ak = fmaf(x, sWk[c * 64 + lane], ak);
            av = fmaf(x, sWv[c * 64 + lane], av);
        }
        int grow = row0 + r;
        int b = grow >> 10, l = grow & 1023;
        int h = lane >> 3, kk = lane & 7;
        int o = ((b * 8 + h) * 1024 + l) * 8 + kk;
        q[o] = aq; k[o] = ak; v[o] = av;
    }
}

// ---------------------------------------------------------------- attention (flash-style, 2 passes)
// One thread = one query row. K/V for the (b,h) staged in LDS; reads are wave-uniform broadcasts.
__global__ __launch_bounds__(256) void attn_kernel(
    const float* __restrict__ q, const float* __restrict__ k, const float* __restrict__ v,
    const float* __restrict__ mask, float* __restrict__ O)
{
    __shared__ __align__(16) float sK[8192];
    __shared__ __align__(16) float sV[8192];
    __shared__ float sM[1024];
    int tid = threadIdx.x;
    int bh = blockIdx.x >> 2;
    int quarter = blockIdx.x & 3;
    int b = bh >> 3;
    const float* kb = k + bh * 8192;
    const float* vbp = v + bh * 8192;
    for (int idx = tid; idx < 8192; idx += 256) { sK[idx] = kb[idx]; sV[idx] = vbp[idx]; }
    for (int idx = tid; idx < 1024; idx += 256) sM[idx] = mask[b * 1024 + idx];
    __syncthreads();
    int l = quarter * 256 + tid;
    const float4* qp = reinterpret_cast<const float4*>(q + (bh * 1024 + l) * 8);
    float4 q0 = qp[0], q1 = qp[1];
    // pass 1: row max (masked score is exactly -1e-30, per reference)
    float mx = -INFINITY;
    for (int m = 0; m < 1024; ++m) {
        const float4* kp = reinterpret_cast<const float4*>(sK + m * 8);
        float4 k0 = kp[0], k1 = kp[1];
        float s = q0.x*k0.x + q0.y*k0.y + q0.z*k0.z + q0.w*k0.w
                + q1.x*k1.x + q1.y*k1.y + q1.z*k1.z + q1.w*k1.w;
        s = (sM[m] != 0.0f) ? s : -1e-30f;
        mx = fmaxf(mx, s);
    }
    // pass 2: exp-sum and PV accumulate
    float sum = 0.f;
    float4 a0 = make_float4(0.f,0.f,0.f,0.f), a1 = make_float4(0.f,0.f,0.f,0.f);
    for (int m = 0; m < 1024; ++m) {
        const float4* kp = reinterpret_cast<const float4*>(sK + m * 8);
        float4 k0 = kp[0], k1 = kp[1];
        float s = q0.x*k0.x + q0.y*k0.y + q0.z*k0.z + q0.w*k0.w
                + q1.x*k1.x + q1.y*k1.y + q1.z*k1.z + q1.w*k1.w;
        s = (sM[m] != 0.0f) ? s : -1e-30f;
        float p = __expf(s - mx);
        sum += p;
        const float4* vp = reinterpret_cast<const float4*>(sV + m * 8);
        float4 v0 = vp[0], v1 = vp[1];
        a0.x = fmaf(p, v0.x, a0.x); a0.y = fmaf(p, v0.y, a0.y);
        a0.z = fmaf(p, v0.z, a0.z); a0.w = fmaf(p, v0.w, a0.w);
        a1.x = fmaf(p, v1.x, a1.x); a1.y = fmaf(p, v1.y, a1.y);
        a1.z = fmaf(p, v1.z, a1.z); a1.w = fmaf(p, v1.w, a1.w);
    }
    float inv = 1.0f / sum;
    float4* op = reinterpret_cast<float4*>(O + (bh * 1024 + l) * 8);
    op[0] = make_float4(a0.x*inv, a0.y*inv, a0.z*inv, a0.w*inv);
    op[1] = make_float4(a1.x*inv, a1.y*inv, a1.z*inv, a1.w*inv);
}

// ---------------------------------------------------------------- out-proj + residual + LN (wave = row)
__global__ __launch_bounds__(256) void proj_ln_kernel(
    float* __restrict__ X, const float* __restrict__ O, const float* __restrict__ Wo,
    const float* __restrict__ gamma, const float* __restrict__ beta, int gi)
{
    __shared__ float sWo[4096];
    __shared__ float so[4][64];
    int tid = threadIdx.x;
    for (int idx = tid; idx < 4096; idx += 256) sWo[idx] = Wo[idx];
    int row0 = blockIdx.x * 4;
    {
        int r = tid >> 6, j = tid & 63;
        int grow = row0 + r;
        int b = grow >> 10, l = grow & 1023;
        so[r][j] = O[((b * 8 + (j >> 3)) * 1024 + l) * 8 + (j & 7)];
    }
    __syncthreads();
    int r = tid >> 6, c = tid & 63;
    float acc = 0.f;
#pragma unroll 8
    for (int j = 0; j < 64; ++j) acc = fmaf(so[r][j], sWo[j * 64 + c], acc);
    float x = X[(row0 + r) * 64 + c] + acc;
    float mean = wave_sum64(x) * (1.0f / 64.0f);
    float dx = x - mean;
    float var = wave_sum64(dx * dx) * (1.0f / 64.0f);
    X[(row0 + r) * 64 + c] = dx * rsqrtf(var + 1e-14f) * gamma[gi] + beta[gi];
}

// ---------------------------------------------------------------- FFN + residual + LN
__global__ __launch_bounds__(256) void ffn_ln_kernel(
    float* __restrict__ X, const float* __restrict__ W1, const float* __restrict__ b1,
    const float* __restrict__ W2, const float* __restrict__ b2,
    const float* __restrict__ gamma, const float* __restrict__ beta, int gi)
{
    __shared__ float sW1[8192];  // [c][j]
    __shared__ float sW2[8192];  // [j][c]
    __shared__ float sX[1024];
    __shared__ float sh[2048];
    int tid = threadIdx.x;
    for (int idx = tid; idx < 8192; idx += 256) { sW1[idx] = W1[idx]; sW2[idx] = W2[idx]; }
    int row0 = blockIdx.x * 16;
    for (int idx = tid; idx < 1024; idx += 256) sX[idx] = X[row0 * 64 + idx];
    __syncthreads();
    for (int idx = tid; idx < 2048; idx += 256) {
        int r = idx >> 7, j = idx & 127;
        float a = b1[j];
#pragma unroll 8
        for (int c = 0; c < 64; ++c) a = fmaf(sX[r * 64 + c], sW1[c * 128 + j], a);
        sh[idx] = fmaxf(a, 0.0f);
    }
    __syncthreads();
#pragma unroll
    for (int iter = 0; iter < 4; ++iter) {
        int idx = iter * 256 + tid;
        int r = idx >> 6, c = idx & 63;
        float a = b2[c];
#pragma unroll 8
        for (int j = 0; j < 128; ++j) a = fmaf(sh[r * 128 + j], sW2[j * 64 + c], a);
        float x = sX[idx] + a;
        float mean = wave_sum64(x) * (1.0f / 64.0f);
        float dx = x - mean;
        float var = wave_sum64(dx * dx) * (1.0f / 64.0f);
        X[row0 * 64 + idx] = dx * rsqrtf(var + 1e-14f) * gamma[gi] + beta[gi];
    }
}

// ---------------------------------------------------------------- pooling attention weights
__global__ __launch_bounds__(256) void aw_kernel(
    const float* __restrict__ X, const float* __restrict__ aW1, const float* __restrict__ ab1,
    const float* __restrict__ aW2, float* __restrict__ aw)
{
    __shared__ float sW[8192];   // aW1 [c][j]
    __shared__ float sX[1024];
    __shared__ float sh[2048];
    int tid = threadIdx.x;
    for (int idx = tid; idx < 8192; idx += 256) sW[idx] = aW1[idx];
    int row0 = blockIdx.x * 16;
    for (int idx = tid; idx < 1024; idx += 256) sX[idx] = X[row0 * 64 + idx];
    __syncthreads();
    for (int idx = tid; idx < 2048; idx += 256) {
        int r = idx >> 7, j = idx & 127;
        float a = ab1[j];
#pragma unroll 8
        for (int c = 0; c < 64; ++c) a = fmaf(sX[r * 64 + c], sW[c * 128 + j], a);
        sh[idx] = tanhf(a) * aW2[j];
    }
    __syncthreads();
    {
        int r = tid >> 4, jj = tid & 15;
        float s = 0.f;
#pragma unroll
        for (int t = 0; t < 8; ++t) s += sh[r * 128 + jj * 8 + t];
#pragma unroll
        for (int off = 8; off > 0; off >>= 1) s += __shfl_xor(s, off, 64);
        if (jj == 0) aw[row0 + r] = s;
    }
}

// ---------------------------------------------------------------- masked pool softmax + final head
__global__ __launch_bounds__(256) void pool_kernel(
    const float* __restrict__ X, const float* __restrict__ aw,
    const float* __restrict__ mask, const float* __restrict__ denc,
    const float* __restrict__ Wout, const float* __restrict__ bout, float* __restrict__ out)
{
    __shared__ float sp[1024];
    __shared__ float red[8];
    __shared__ float sf[4][64];
    int b = blockIdx.x, tid = threadIdx.x;
    float mymax = -INFINITY;
    for (int idx = tid; idx < 1024; idx += 256) {
        float s = (mask[b * 1024 + idx] != 0.0f) ? aw[b * 1024 + idx] : -1e30f;
        sp[idx] = s;
        mymax = fmaxf(mymax, s);
    }
#pragma unroll
    for (int off = 32; off > 0; off >>= 1) mymax = fmaxf(mymax, __shfl_xor(mymax, off, 64));
    if ((tid & 63) == 0) red[tid >> 6] = mymax;
    __syncthreads();
    float gmax = fmaxf(fmaxf(red[0], red[1]), fmaxf(red[2], red[3]));
    float mysum = 0.f;
    for (int idx = tid; idx < 1024; idx += 256) {
        float p = __expf(sp[idx] - gmax);
        sp[idx] = p;
        mysum += p;
    }
    mysum = wave_sum64(mysum);
    if ((tid & 63) == 0) red[4 + (tid >> 6)] = mysum;
    __syncthreads();
    float inv = 1.0f / (red[4] + red[5] + red[6] + red[7]);
    int c = tid & 63, part = tid >> 6;
    float f = 0.f;
    for (int l = part; l < 1024; l += 4) f = fmaf(sp[l], X[(b * 1024 + l) * 64 + c], f);
    sf[part][c] = f;
    __syncthreads();
    if (tid < 64) {
        float fc = (sf[0][tid] + sf[1][tid] + sf[2][tid] + sf[3][tid]) * inv;
        float contrib = fc * Wout[tid] + denc[b * 64 + tid] * Wout[64 + tid];
        contrib = wave_sum64(contrib);
        if (tid == 0) out[b] = 1.0f / (1.0f + __expf(-(contrib + bout[0])));
    }
}

// ---------------------------------------------------------------- launch
extern "C" void kernel_launch(void* const* d_in, const int* in_sizes, int n_in,
                              void* d_out, int out_size, void* d_ws, size_t ws_size,
                              hipStream_t stream)
{
    const float* demo  = (const float*)d_in[0];
    const float* times = (const float*)d_in[1];
    const float* values= (const float*)d_in[2];
    const int*   varis = (const int*)d_in[3];
    const float* emb   = (const float*)d_in[4];
    const float* vW1   = (const float*)d_in[5];
    const float* vb1   = (const float*)d_in[6];
    const float* vW2   = (const float*)d_in[7];
    const float* tW1   = (const float*)d_in[8];
    const float* tb1   = (const float*)d_in[9];
    const float* tW2   = (const float*)d_in[10];
    const float* Wq    = (const float*)d_in[11];
    const float* Wk    = (const float*)d_in[12];
    const float* Wv    = (const float*)d_in[13];
    const float* Wo    = (const float*)d_in[14];
    const float* W1    = (const float*)d_in[15];
    const float* b1    = (const float*)d_in[16];
    const float* W2    = (const float*)d_in[17];
    const float* b2    = (const float*)d_in[18];
    const float* gamma = (const float*)d_in[19];
    const float* beta  = (const float*)d_in[20];
    const float* aW1   = (const float*)d_in[21];
    const float* ab1   = (const float*)d_in[22];
    const float* aW2   = (const float*)d_in[23];
    const float* dW1   = (const float*)d_in[24];
    const float* db1   = (const float*)d_in[25];
    const float* dW2   = (const float*)d_in[26];
    const float* db2   = (const float*)d_in[27];
    const float* Wout  = (const float*)d_in[28];
    const float* bout  = (const float*)d_in[29];
    float* out = (float*)d_out;

    float* ws   = (float*)d_ws;
    float* X    = ws;                  // 1048576 f
    float* mask = X + 1048576;         // 16384 f
    float* qb   = mask + 16384;        // 1048576 f
    float* kb   = qb + 1048576;        // 1048576 f
    float* vb   = kb + 1048576;        // 1048576 f
    float* Ob   = vb + 1048576;        // 1048576 f
    float* awb  = Ob + 1048576;        // 16384 f
    float* denc = awb + 16384;         // 1024 f

    embed_kernel<<<4096, 256, 0, stream>>>(times, values, varis, emb, vW1, vb1, vW2, tW1, tb1, tW2, X, mask);
    demo_kernel<<<16, 128, 0, stream>>>(demo, dW1, db1, dW2, db2, denc);
    for (int i = 0; i < 2; ++i) {
        qkv_kernel<<<256, 256, 0, stream>>>(X, Wq + i * 4096, Wk + i * 4096, Wv + i * 4096, qb, kb, vb);
        attn_kernel<<<512, 256, 0, stream>>>(qb, kb, vb, mask, Ob);
        proj_ln_kernel<<<4096, 256, 0, stream>>>(X, Ob, Wo + i * 4096, gamma, beta, 2 * i);
        ffn_ln_kernel<<<1024, 256, 0, stream>>>(X, W1 + i * 8192, b1 + i * 128, W2 + i * 8192, b2 + i * 64,
                                                gamma, beta, 2 * i + 1);
    }
    aw_kernel<<<1024, 256, 0, stream>>>(X, aW1, ab1, aW2, awb);
    pool_kernel<<<16, 256, 0, stream>>>(X, awb, mask, denc, Wout, bout, out);
}

// Round 2
// 421.780 us; speedup vs baseline: 1.4887x; 1.4887x over previous
//
#include <hip/hip_runtime.h>
#include <math.h>

// Sizes (fixed): B=16, L=1024, D=50, V=129, d=64, N=2, H=8, DK=8, DFF=128, CVE=8
// LN eps = 1e-14, MASK_ATTN = -1e-30 (~zero!), MASK_POOL = -1e30.

typedef __bf16 bf16x8 __attribute__((ext_vector_type(8)));
typedef float f32x16 __attribute__((ext_vector_type(16)));
typedef unsigned int uint4e __attribute__((ext_vector_type(4)));

static __device__ __forceinline__ float wave_sum64(float x) {
#pragma unroll
    for (int off = 32; off > 0; off >>= 1) x += __shfl_xor(x, off, 64);
    return x;
}

static __device__ __forceinline__ unsigned pack2(float a, float b) {
    __bf16 x = (__bf16)a, y = (__bf16)b;
    unsigned short ux = __builtin_bit_cast(unsigned short, x);
    unsigned short uy = __builtin_bit_cast(unsigned short, y);
    return (unsigned)ux | ((unsigned)uy << 16);
}

// lo <- value held by the hi=0 lane of the (lane, lane^32) pair; hi_ <- hi=1 lane's value.
static __device__ __forceinline__ void plswap(unsigned v, unsigned& lo, unsigned& hi_) {
#if defined(__has_builtin) && __has_builtin(__builtin_amdgcn_permlane32_swap)
    auto r = __builtin_amdgcn_permlane32_swap(v, v, false, false);
    lo = r[0]; hi_ = r[1];
#else
    unsigned x = __shfl_xor(v, 32, 64);
    bool h = (threadIdx.x & 32) != 0;
    lo = h ? x : v;
    hi_ = h ? v : x;
#endif
}

// ---------------------------------------------------------------- embeddings
__global__ __launch_bounds__(256) void embed_kernel(
    const float* __restrict__ times, const float* __restrict__ values,
    const int* __restrict__ varis, const float* __restrict__ emb,
    const float* __restrict__ vW1, const float* __restrict__ vb1, const float* __restrict__ vW2,
    const float* __restrict__ tW1, const float* __restrict__ tb1, const float* __restrict__ tW2,
    float* __restrict__ X, float* __restrict__ mask)
{
    int row = blockIdx.x * 4 + (threadIdx.x >> 6);  // (b*L + l)
    int c   = threadIdx.x & 63;
    float v = values[row];
    float t = times[row];
    int var = varis[row];
    if (c == 0) mask[row] = (var > 0) ? 1.0f : 0.0f;
    float acc = emb[var * 64 + c];
#pragma unroll
    for (int j = 0; j < 8; ++j) {
        acc += tanhf(fmaf(v, vW1[j], vb1[j])) * vW2[j * 64 + c];
        acc += tanhf(fmaf(t, tW1[j], tb1[j])) * tW2[j * 64 + c];
    }
    X[row * 64 + c] = acc;
}

// ---------------------------------------------------------------- demo encoder
__global__ __launch_bounds__(128) void demo_kernel(
    const float* __restrict__ demo, const float* __restrict__ dW1, const float* __restrict__ db1,
    const float* __restrict__ dW2, const float* __restrict__ db2, float* __restrict__ denc)
{
    __shared__ float sh[128];
    int b = blockIdx.x;
    int t = threadIdx.x;
    float a = db1[t];
    for (int j = 0; j < 50; ++j) a = fmaf(demo[b * 50 + j], dW1[j * 128 + t], a);
    sh[t] = tanhf(a);
    __syncthreads();
    if (t < 64) {
        float a2 = db2[t];
#pragma unroll 8
        for (int j = 0; j < 128; ++j) a2 = fmaf(sh[j], dW2[j * 64 + t], a2);
        denc[b * 64 + t] = tanhf(a2);
    }
}

// ---------------------------------------------------------------- qkv projection
__global__ __launch_bounds__(256) void qkv_kernel(
    const float* __restrict__ X,
    const float* __restrict__ Wq, const float* __restrict__ Wk, const float* __restrict__ Wv,
    float* __restrict__ q, float* __restrict__ k, float* __restrict__ v)
{
    __shared__ float sWq[4096], sWk[4096], sWv[4096], sX[4096];
    int tid = threadIdx.x;
    for (int idx = tid; idx < 4096; idx += 256) {
        int h = idx >> 9, c = (idx >> 3) & 63, kk = idx & 7;
        int l = c * 64 + h * 8 + kk;
        sWq[l] = Wq[idx];
        sWk[l] = Wk[idx];
        sWv[l] = Wv[idx];
    }
    int row0 = blockIdx.x * 64;
    for (int idx = tid; idx < 4096; idx += 256) sX[idx] = X[row0 * 64 + idx];
    __syncthreads();
    int lane = tid & 63;
    for (int iter = 0; iter < 16; ++iter) {
        int r = iter * 4 + (tid >> 6);
        float aq = 0.f, ak = 0.f, av = 0.f;
#pragma unroll 8
        for (int c = 0; c < 64; ++c) {
            float x = sX[r * 64 + c];
            aq = fmaf(x, sWq[c * 64 + lane], aq);
            ak = fmaf(x, sWk[c * 64 + lane], ak);
            av = fmaf(x, sWv[c * 64 + lane], av);
        }
        int grow = row0 + r;
        int b = grow >> 10, l = grow & 1023;
        int h = lane >> 3, kk = lane & 7;
        int o = ((b * 8 + h) * 1024 + l) * 8 + kk;
        q[o] = aq; k[o] = ak; v[o] = av;
    }
}

// ---------------------------------------------------------------- MFMA attention
// Swapped QK^T (A=K, B=Q) with 32x32x16 bf16 MFMA: S^T col = lane&31 = query -> softmax
// is lane-local. No max-subtraction (shift-invariant; masked score -1e-30 -> exp = 1.0).
// PV as O^T = mfma(V^T, P^T, acc). One wave = 32 queries; block = 4 waves = 128 queries.
__global__ __launch_bounds__(256, 4) void attn_mfma_kernel(
    const float* __restrict__ q, const float* __restrict__ k, const float* __restrict__ v,
    const float* __restrict__ mask, float* __restrict__ O)
{
    __shared__ __align__(16) __bf16 sK[8192];       // [key][8] bf16
    __shared__ __align__(16) __bf16 sVT[8 * 1032];  // [dk][1032] bf16 (padded stride)
    __shared__ __align__(16) float  sM[1024];

    int tid = threadIdx.x;
    int bh = blockIdx.x >> 3;
    int b  = bh >> 3;
    const float* kbp = k + bh * 8192;
    const float* vbp = v + bh * 8192;

    // stage K as bf16 pairs (ds_write_b32)
    for (int i = tid; i < 4096; i += 256) {
        float2 kv = ((const float2*)kbp)[i];
        ((unsigned*)sK)[i] = pack2(kv.x, kv.y);
    }
    // stage V transposed: sVT[dk][key]
    for (int i = tid; i < 4096; i += 256) {
        int key = i >> 2, dp = i & 3;
        float2 vv = ((const float2*)vbp)[i];   // = V[key][2dp..2dp+1]
        sVT[(2 * dp) * 1032 + key]     = (__bf16)vv.x;
        sVT[(2 * dp + 1) * 1032 + key] = (__bf16)vv.y;
    }
    for (int i = tid; i < 1024; i += 256) sM[i] = mask[b * 1024 + i];
    __syncthreads();

    int lane = tid & 63;
    int wv   = tid >> 6;
    int hi   = (lane >> 5) & 1;
    int l31  = lane & 31;
    unsigned hm = hi ? 0u : 0xffffffffu;          // zero the k=8..15 padding half
    unsigned vm = (l31 < 8) ? 0xffffffffu : 0u;   // zero V^T rows dk>=8

    int qrow = (blockIdx.x & 7) * 128 + wv * 32 + l31;

    // Q fragment (B operand): lane holds Q[query=l31][dk = 8*hi + j] -> hi half zero
    bf16x8 qf;
    {
        const float* qp = q + (bh * 1024 + qrow) * 8;
        float4 qa = *(const float4*)qp;
        float4 qb = *(const float4*)(qp + 4);
        qf[0] = (__bf16)qa.x; qf[1] = (__bf16)qa.y; qf[2] = (__bf16)qa.z; qf[3] = (__bf16)qa.w;
        qf[4] = (__bf16)qb.x; qf[5] = (__bf16)qb.y; qf[6] = (__bf16)qb.z; qf[7] = (__bf16)qb.w;
        uint4e qw = __builtin_bit_cast(uint4e, qf);
        qw[0] &= hm; qw[1] &= hm; qw[2] &= hm; qw[3] &= hm;
        qf = __builtin_bit_cast(bf16x8, qw);
    }

    f32x16 acc, zc;
#pragma unroll
    for (int i = 0; i < 16; ++i) { acc[i] = 0.f; zc[i] = 0.f; }
    float psum = 0.f;
    const bf16x8* sKv = (const bf16x8*)sK;

    for (int kt = 0; kt < 32; ++kt) {
        int kb0 = kt * 32;
        // K fragment (A operand): row = key, k = 8*hi + j (hi half zero-padded)
        bf16x8 kf = sKv[kb0 + l31];
        {
            uint4e kw = __builtin_bit_cast(uint4e, kf);
            kw[0] &= hm; kw[1] &= hm; kw[2] &= hm; kw[3] &= hm;
            kf = __builtin_bit_cast(bf16x8, kw);
        }
        // S^T[key][query]: reg r -> key = kb0 + (r&3) + 8*(r>>2) + 4*hi, query = l31
        f32x16 st = __builtin_amdgcn_mfma_f32_32x32x16_bf16(kf, qf, zc, 0, 0, 0);

        float4 m0 = *(const float4*)(sM + kb0 + 4 * hi);
        float4 m1 = *(const float4*)(sM + kb0 + 8 + 4 * hi);
        float4 m2 = *(const float4*)(sM + kb0 + 16 + 4 * hi);
        float4 m3 = *(const float4*)(sM + kb0 + 24 + 4 * hi);
        float mv[16] = { m0.x, m0.y, m0.z, m0.w, m1.x, m1.y, m1.z, m1.w,
                         m2.x, m2.y, m2.z, m2.w, m3.x, m3.y, m3.z, m3.w };
        float p[16];
#pragma unroll
        for (int r = 0; r < 16; ++r) {
            float sm = (mv[r] != 0.0f) ? st[r] : -1e-30f;
            p[r] = __expf(sm);
        }
        // pairwise tree sum
        float a0 = (p[0] + p[1]) + (p[2] + p[3]);
        float a1 = (p[4] + p[5]) + (p[6] + p[7]);
        float a2 = (p[8] + p[9]) + (p[10] + p[11]);
        float a3 = (p[12] + p[13]) + (p[14] + p[15]);
        psum += (a0 + a1) + (a2 + a3);

        // pack to bf16: c0[g] = keys 8g+4hi+{0,1}, c1[g] = 8g+4hi+{2,3}
        unsigned c0[4], c1[4], L0[4], H0[4], L1[4], H1[4];
#pragma unroll
        for (int g = 0; g < 4; ++g) {
            c0[g] = pack2(p[4 * g + 0], p[4 * g + 1]);
            c1[g] = pack2(p[4 * g + 2], p[4 * g + 3]);
            plswap(c0[g], L0[g], H0[g]);
            plswap(c1[g], L1[g], H1[g]);
        }
#pragma unroll
        for (int h = 0; h < 2; ++h) {
            // B operand (P^T): lane needs keys of group g' = 2h+hi in k-order
            unsigned w0 = hi ? L0[2 * h + 1] : L0[2 * h];
            unsigned w1 = hi ? L1[2 * h + 1] : L1[2 * h];
            unsigned w2 = hi ? H0[2 * h + 1] : H0[2 * h];
            unsigned w3 = hi ? H1[2 * h + 1] : H1[2 * h];
            uint4e pw; pw[0] = w0; pw[1] = w1; pw[2] = w2; pw[3] = w3;
            bf16x8 pf = __builtin_bit_cast(bf16x8, pw);
            // A operand (V^T): row = dk (=l31, rows>=8 zeroed), k = key offset 16h+8hi+j
            bf16x8 vf = *(const bf16x8*)(sVT + (l31 & 7) * 1032 + kb0 + 16 * h + 8 * hi);
            uint4e vw = __builtin_bit_cast(uint4e, vf);
            vw[0] &= vm; vw[1] &= vm; vw[2] &= vm; vw[3] &= vm;
            vf = __builtin_bit_cast(bf16x8, vw);
            acc = __builtin_amdgcn_mfma_f32_32x32x16_bf16(vf, pf, acc, 0, 0, 0);
        }
    }

    float tot = psum + __shfl_xor(psum, 32, 64);
    float inv = 1.0f / tot;
    // acc regs 0..3 hold O^T rows dk = 4*hi + j for query l31
    float4 o;
    o.x = acc[0] * inv; o.y = acc[1] * inv; o.z = acc[2] * inv; o.w = acc[3] * inv;
    *(float4*)(O + (bh * 1024 + qrow) * 8 + 4 * hi) = o;
}

// ---------------------------------------------------------------- out-proj + residual + LN (wave = row)
__global__ __launch_bounds__(256) void proj_ln_kernel(
    float* __restrict__ X, const float* __restrict__ O, const float* __restrict__ Wo,
    const float* __restrict__ gamma, const float* __restrict__ beta, int gi)
{
    __shared__ float sWo[4096];
    __shared__ float so[4][64];
    int tid = threadIdx.x;
    for (int idx = tid; idx < 4096; idx += 256) sWo[idx] = Wo[idx];
    int row0 = blockIdx.x * 4;
    {
        int r = tid >> 6, j = tid & 63;
        int grow = row0 + r;
        int b = grow >> 10, l = grow & 1023;
        so[r][j] = O[((b * 8 + (j >> 3)) * 1024 + l) * 8 + (j & 7)];
    }
    __syncthreads();
    int r = tid >> 6, c = tid & 63;
    float acc = 0.f;
#pragma unroll 8
    for (int j = 0; j < 64; ++j) acc = fmaf(so[r][j], sWo[j * 64 + c], acc);
    float x = X[(row0 + r) * 64 + c] + acc;
    float mean = wave_sum64(x) * (1.0f / 64.0f);
    float dx = x - mean;
    float var = wave_sum64(dx * dx) * (1.0f / 64.0f);
    X[(row0 + r) * 64 + c] = dx * rsqrtf(var + 1e-14f) * gamma[gi] + beta[gi];
}

// ---------------------------------------------------------------- FFN + residual + LN
__global__ __launch_bounds__(256) void ffn_ln_kernel(
    float* __restrict__ X, const float* __restrict__ W1, const float* __restrict__ b1,
    const float* __restrict__ W2, const float* __restrict__ b2,
    const float* __restrict__ gamma, const float* __restrict__ beta, int gi)
{
    __shared__ float sW1[8192];  // [c][j]
    __shared__ float sW2[8192];  // [j][c]
    __shared__ float sX[1024];
    __shared__ float sh[2048];
    int tid = threadIdx.x;
    for (int idx = tid; idx < 8192; idx += 256) { sW1[idx] = W1[idx]; sW2[idx] = W2[idx]; }
    int row0 = blockIdx.x * 16;
    for (int idx = tid; idx < 1024; idx += 256) sX[idx] = X[row0 * 64 + idx];
    __syncthreads();
    for (int idx = tid; idx < 2048; idx += 256) {
        int r = idx >> 7, j = idx & 127;
        float a = b1[j];
#pragma unroll 8
        for (int c = 0; c < 64; ++c) a = fmaf(sX[r * 64 + c], sW1[c * 128 + j], a);
        sh[idx] = fmaxf(a, 0.0f);
    }
    __syncthreads();
#pragma unroll
    for (int iter = 0; iter < 4; ++iter) {
        int idx = iter * 256 + tid;
        int r = idx >> 6, c = idx & 63;
        float a = b2[c];
#pragma unroll 8
        for (int j = 0; j < 128; ++j) a = fmaf(sh[r * 128 + j], sW2[j * 64 + c], a);
        float x = sX[idx] + a;
        float mean = wave_sum64(x) * (1.0f / 64.0f);
        float dx = x - mean;
        float var = wave_sum64(dx * dx) * (1.0f / 64.0f);
        X[row0 * 64 + idx] = dx * rsqrtf(var + 1e-14f) * gamma[gi] + beta[gi];
    }
}

// ---------------------------------------------------------------- pooling attention weights
__global__ __launch_bounds__(256) void aw_kernel(
    const float* __restrict__ X, const float* __restrict__ aW1, const float* __restrict__ ab1,
    const float* __restrict__ aW2, float* __restrict__ aw)
{
    __shared__ float sW[8192];   // aW1 [c][j]
    __shared__ float sX[1024];
    __shared__ float sh[2048];
    int tid = threadIdx.x;
    for (int idx = tid; idx < 8192; idx += 256) sW[idx] = aW1[idx];
    int row0 = blockIdx.x * 16;
    for (int idx = tid; idx < 1024; idx += 256) sX[idx] = X[row0 * 64 + idx];
    __syncthreads();
    for (int idx = tid; idx < 2048; idx += 256) {
        int r = idx >> 7, j = idx & 127;
        float a = ab1[j];
#pragma unroll 8
        for (int c = 0; c < 64; ++c) a = fmaf(sX[r * 64 + c], sW[c * 128 + j], a);
        sh[idx] = tanhf(a) * aW2[j];
    }
    __syncthreads();
    {
        int r = tid >> 4, jj = tid & 15;
        float s = 0.f;
#pragma unroll
        for (int t = 0; t < 8; ++t) s += sh[r * 128 + jj * 8 + t];
#pragma unroll
        for (int off = 8; off > 0; off >>= 1) s += __shfl_xor(s, off, 64);
        if (jj == 0) aw[row0 + r] = s;
    }
}

// ---------------------------------------------------------------- masked pool softmax + final head
__global__ __launch_bounds__(256) void pool_kernel(
    const float* __restrict__ X, const float* __restrict__ aw,
    const float* __restrict__ mask, const float* __restrict__ denc,
    const float* __restrict__ Wout, const float* __restrict__ bout, float* __restrict__ out)
{
    __shared__ float sp[1024];
    __shared__ float red[8];
    __shared__ float sf[4][64];
    int b = blockIdx.x, tid = threadIdx.x;
    float mymax = -INFINITY;
    for (int idx = tid; idx < 1024; idx += 256) {
        float s = (mask[b * 1024 + idx] != 0.0f) ? aw[b * 1024 + idx] : -1e30f;
        sp[idx] = s;
        mymax = fmaxf(mymax, s);
    }
#pragma unroll
    for (int off = 32; off > 0; off >>= 1) mymax = fmaxf(mymax, __shfl_xor(mymax, off, 64));
    if ((tid & 63) == 0) red[tid >> 6] = mymax;
    __syncthreads();
    float gmax = fmaxf(fmaxf(red[0], red[1]), fmaxf(red[2], red[3]));
    float mysum = 0.f;
    for (int idx = tid; idx < 1024; idx += 256) {
        float p = __expf(sp[idx] - gmax);
        sp[idx] = p;
        mysum += p;
    }
    mysum = wave_sum64(mysum);
    if ((tid & 63) == 0) red[4 + (tid >> 6)] = mysum;
    __syncthreads();
    float inv = 1.0f / (red[4] + red[5] + red[6] + red[7]);
    int c = tid & 63, part = tid >> 6;
    float f = 0.f;
    for (int l = part; l < 1024; l += 4) f = fmaf(sp[l], X[(b * 1024 + l) * 64 + c], f);
    sf[part][c] = f;
    __syncthreads();
    if (tid < 64) {
        float fc = (sf[0][tid] + sf[1][tid] + sf[2][tid] + sf[3][tid]) * inv;
        float contrib = fc * Wout[tid] + denc[b * 64 + tid] * Wout[64 + tid];
        contrib = wave_sum64(contrib);
        if (tid == 0) out[b] = 1.0f / (1.0f + __expf(-(contrib + bout[0])));
    }
}

// ---------------------------------------------------------------- launch
extern "C" void kernel_launch(void* const* d_in, const int* in_sizes, int n_in,
                              void* d_out, int out_size, void* d_ws, size_t ws_size,
                              hipStream_t stream)
{
    const float* demo  = (const float*)d_in[0];
    const float* times = (const float*)d_in[1];
    const float* values= (const float*)d_in[2];
    const int*   varis = (const int*)d_in[3];
    const float* emb   = (const float*)d_in[4];
    const float* vW1   = (const float*)d_in[5];
    const float* vb1   = (const float*)d_in[6];
    const float* vW2   = (const float*)d_in[7];
    const float* tW1   = (const float*)d_in[8];
    const float* tb1   = (const float*)d_in[9];
    const float* tW2   = (const float*)d_in[10];
    const float* Wq    = (const float*)d_in[11];
    const float* Wk    = (const float*)d_in[12];
    const float* Wv    = (const float*)d_in[13];
    const float* Wo    = (const float*)d_in[14];
    const float* W1    = (const float*)d_in[15];
    const float* b1    = (const float*)d_in[16];
    const float* W2    = (const float*)d_in[17];
    const float* b2    = (const float*)d_in[18];
    const float* gamma = (const float*)d_in[19];
    const float* beta  = (const float*)d_in[20];
    const float* aW1   = (const float*)d_in[21];
    const float* ab1   = (const float*)d_in[22];
    const float* aW2   = (const float*)d_in[23];
    const float* dW1   = (const float*)d_in[24];
    const float* db1   = (const float*)d_in[25];
    const float* dW2   = (const float*)d_in[26];
    const float* db2   = (const float*)d_in[27];
    const float* Wout  = (const float*)d_in[28];
    const float* bout  = (const float*)d_in[29];
    float* out = (float*)d_out;

    float* ws   = (float*)d_ws;
    float* X    = ws;                  // 1048576 f
    float* mask = X + 1048576;         // 16384 f
    float* qb   = mask + 16384;        // 1048576 f
    float* kb   = qb + 1048576;        // 1048576 f
    float* vb   = kb + 1048576;        // 1048576 f
    float* Ob   = vb + 1048576;        // 1048576 f
    float* awb  = Ob + 1048576;        // 16384 f
    float* denc = awb + 16384;         // 1024 f

    embed_kernel<<<4096, 256, 0, stream>>>(times, values, varis, emb, vW1, vb1, vW2, tW1, tb1, tW2, X, mask);
    demo_kernel<<<16, 128, 0, stream>>>(demo, dW1, db1, dW2, db2, denc);
    for (int i = 0; i < 2; ++i) {
        qkv_kernel<<<256, 256, 0, stream>>>(X, Wq + i * 4096, Wk + i * 4096, Wv + i * 4096, qb, kb, vb);
        attn_mfma_kernel<<<1024, 256, 0, stream>>>(qb, kb, vb, mask, Ob);
        proj_ln_kernel<<<4096, 256, 0, stream>>>(X, Ob, Wo + i * 4096, gamma, beta, 2 * i);
        ffn_ln_kernel<<<1024, 256, 0, stream>>>(X, W1 + i * 8192, b1 + i * 128, W2 + i * 8192, b2 + i * 64,
                                                gamma, beta, 2 * i + 1);
    }
    aw_kernel<<<1024, 256, 0, stream>>>(X, aW1, ab1, aW2, awb);
    pool_kernel<<<16, 256, 0, stream>>>(X, awb, mask, denc, Wout, bout, out);
}

// Round 3
// 401.414 us; speedup vs baseline: 1.5642x; 1.0507x over previous
//
#include <hip/hip_runtime.h>
#include <math.h>

// Sizes (fixed): B=16, L=1024, D=50, V=129, d=64, N=2, H=8, DK=8, DFF=128, CVE=8
// LN eps = 1e-14, MASK_ATTN = -1e-30 (~zero!), MASK_POOL = -1e30.

typedef __bf16 bf16x8 __attribute__((ext_vector_type(8)));
typedef float f32x16 __attribute__((ext_vector_type(16)));
typedef unsigned int uint4e __attribute__((ext_vector_type(4)));

static __device__ __forceinline__ float wave_sum64(float x) {
#pragma unroll
    for (int off = 32; off > 0; off >>= 1) x += __shfl_xor(x, off, 64);
    return x;
}

static __device__ __forceinline__ unsigned pack2(float a, float b) {
    __bf16 x = (__bf16)a, y = (__bf16)b;
    unsigned short ux = __builtin_bit_cast(unsigned short, x);
    unsigned short uy = __builtin_bit_cast(unsigned short, y);
    return (unsigned)ux | ((unsigned)uy << 16);
}

static __device__ __forceinline__ float exp2fast(float x) {
#if defined(__has_builtin) && __has_builtin(__builtin_amdgcn_exp2f)
    return __builtin_amdgcn_exp2f(x);
#else
    return exp2f(x);
#endif
}

// lo <- value held by the hi=0 lane of the (lane, lane^32) pair; hi_ <- hi=1 lane's value.
static __device__ __forceinline__ void plswap(unsigned v, unsigned& lo, unsigned& hi_) {
#if defined(__has_builtin) && __has_builtin(__builtin_amdgcn_permlane32_swap)
    auto r = __builtin_amdgcn_permlane32_swap(v, v, false, false);
    lo = r[0]; hi_ = r[1];
#else
    unsigned x = __shfl_xor(v, 32, 64);
    bool h = (threadIdx.x & 32) != 0;
    lo = h ? x : v;
    hi_ = h ? v : x;
#endif
}

// ---------------------------------------------------------------- embeddings
__global__ __launch_bounds__(256) void embed_kernel(
    const float* __restrict__ times, const float* __restrict__ values,
    const int* __restrict__ varis, const float* __restrict__ emb,
    const float* __restrict__ vW1, const float* __restrict__ vb1, const float* __restrict__ vW2,
    const float* __restrict__ tW1, const float* __restrict__ tb1, const float* __restrict__ tW2,
    float* __restrict__ X, float* __restrict__ mask)
{
    int row = blockIdx.x * 4 + (threadIdx.x >> 6);  // (b*L + l)
    int c   = threadIdx.x & 63;
    float v = values[row];
    float t = times[row];
    int var = varis[row];
    if (c == 0) mask[row] = (var > 0) ? 1.0f : 0.0f;
    float acc = emb[var * 64 + c];
#pragma unroll
    for (int j = 0; j < 8; ++j) {
        acc += tanhf(fmaf(v, vW1[j], vb1[j])) * vW2[j * 64 + c];
        acc += tanhf(fmaf(t, tW1[j], tb1[j])) * tW2[j * 64 + c];
    }
    X[row * 64 + c] = acc;
}

// ---------------------------------------------------------------- demo encoder
__global__ __launch_bounds__(128) void demo_kernel(
    const float* __restrict__ demo, const float* __restrict__ dW1, const float* __restrict__ db1,
    const float* __restrict__ dW2, const float* __restrict__ db2, float* __restrict__ denc)
{
    __shared__ float sh[128];
    int b = blockIdx.x;
    int t = threadIdx.x;
    float a = db1[t];
    for (int j = 0; j < 50; ++j) a = fmaf(demo[b * 50 + j], dW1[j * 128 + t], a);
    sh[t] = tanhf(a);
    __syncthreads();
    if (t < 64) {
        float a2 = db2[t];
#pragma unroll 8
        for (int j = 0; j < 128; ++j) a2 = fmaf(sh[j], dW2[j * 64 + t], a2);
        denc[b * 64 + t] = tanhf(a2);
    }
}

// ---------------------------------------------------------------- qkv projection
// 1024 blocks x 16 rows: 4 blocks/CU -> 4 waves/SIMD (vs 1 at 256 blocks).
__global__ __launch_bounds__(256) void qkv_kernel(
    const float* __restrict__ X,
    const float* __restrict__ Wq, const float* __restrict__ Wk, const float* __restrict__ Wv,
    float* __restrict__ q, float* __restrict__ k, float* __restrict__ v)
{
    __shared__ float sWq[4096], sWk[4096], sWv[4096], sX[1024];
    int tid = threadIdx.x;
    for (int idx = tid; idx < 4096; idx += 256) {
        int h = idx >> 9, c = (idx >> 3) & 63, kk = idx & 7;
        int l = c * 64 + h * 8 + kk;
        sWq[l] = Wq[idx];
        sWk[l] = Wk[idx];
        sWv[l] = Wv[idx];
    }
    int row0 = blockIdx.x * 16;
    for (int idx = tid; idx < 1024; idx += 256) sX[idx] = X[row0 * 64 + idx];
    __syncthreads();
    int lane = tid & 63;
    for (int iter = 0; iter < 4; ++iter) {
        int r = iter * 4 + (tid >> 6);
        float aq = 0.f, ak = 0.f, av = 0.f;
#pragma unroll 8
        for (int c = 0; c < 64; ++c) {
            float x = sX[r * 64 + c];
            aq = fmaf(x, sWq[c * 64 + lane], aq);
            ak = fmaf(x, sWk[c * 64 + lane], ak);
            av = fmaf(x, sWv[c * 64 + lane], av);
        }
        int grow = row0 + r;
        int b = grow >> 10, l = grow & 1023;
        int h = lane >> 3, kk = lane & 7;
        int o = ((b * 8 + h) * 1024 + l) * 8 + kk;
        q[o] = aq; k[o] = ak; v[o] = av;
    }
}

// ---------------------------------------------------------------- MFMA attention
// Swapped QK^T (A=K, B=Q), 32x32x16 bf16 MFMA: S^T col = lane&31 = query -> softmax is
// lane-local. No max-subtraction (shift-invariant). Mask folded into K staging (masked
// K rows zeroed -> score 0 -> exp=1.0, identical to exp(-1e-30)). Q pre-scaled by log2e
// so p = v_exp(s). psum comes free from a ones-row (dk=8) in the V^T A-operand:
// every lane's acc[4] = sum_k p (lanes l31>=9 also feed the ones row; output rows 9..31
// are garbage but never read). PV: O^T = mfma(V^T, P^T, acc).
__global__ __launch_bounds__(256, 4) void attn_mfma_kernel(
    const float* __restrict__ q, const float* __restrict__ k, const float* __restrict__ v,
    const float* __restrict__ mask, float* __restrict__ O)
{
    __shared__ __align__(16) __bf16 sK[1024 * 8];   // [key][8] bf16, masked keys zeroed
    __shared__ __align__(16) __bf16 sVT[9 * 1032];  // rows 0..7 = V^T (padded), row 8 = ones

    int tid = threadIdx.x;
    int bh = blockIdx.x >> 3;
    int b  = bh >> 3;
    const float4* kbp = (const float4*)(k + bh * 8192);
    const float4* vbp = (const float4*)(v + bh * 8192);
    const float*  mbp = mask + b * 1024;

#pragma unroll
    for (int r = 0; r < 4; ++r) {
        int key = r * 256 + tid;
        unsigned zk = (mbp[key] != 0.0f) ? 0xffffffffu : 0u;
        float4 ka = kbp[key * 2], kc = kbp[key * 2 + 1];
        uint4e kw;
        kw[0] = pack2(ka.x, ka.y) & zk;
        kw[1] = pack2(ka.z, ka.w) & zk;
        kw[2] = pack2(kc.x, kc.y) & zk;
        kw[3] = pack2(kc.z, kc.w) & zk;
        *(uint4e*)(sK + key * 8) = kw;
        float4 va = vbp[key * 2], vc = vbp[key * 2 + 1];
        sVT[0 * 1032 + key] = (__bf16)va.x;
        sVT[1 * 1032 + key] = (__bf16)va.y;
        sVT[2 * 1032 + key] = (__bf16)va.z;
        sVT[3 * 1032 + key] = (__bf16)va.w;
        sVT[4 * 1032 + key] = (__bf16)vc.x;
        sVT[5 * 1032 + key] = (__bf16)vc.y;
        sVT[6 * 1032 + key] = (__bf16)vc.z;
        sVT[7 * 1032 + key] = (__bf16)vc.w;
        sVT[8 * 1032 + key] = (__bf16)1.0f;
    }
    __syncthreads();

    int lane = tid & 63;
    int wv   = tid >> 6;
    int hi   = (lane >> 5) & 1;
    int l31  = lane & 31;

    int qrow = (blockIdx.x & 7) * 128 + wv * 32 + l31;

    // Q fragment (B operand): lane holds Q[query=l31][dk = 8*hi + j]; hi half must be
    // zero (k-padding) -> fold into the log2e prescale.
    float qs = hi ? 0.0f : 1.4426950408889634f;
    bf16x8 qf;
    {
        const float* qp = q + (bh * 1024 + qrow) * 8;
        float4 qa = *(const float4*)qp;
        float4 qb = *(const float4*)(qp + 4);
        qf[0] = (__bf16)(qa.x * qs); qf[1] = (__bf16)(qa.y * qs);
        qf[2] = (__bf16)(qa.z * qs); qf[3] = (__bf16)(qa.w * qs);
        qf[4] = (__bf16)(qb.x * qs); qf[5] = (__bf16)(qb.y * qs);
        qf[6] = (__bf16)(qb.z * qs); qf[7] = (__bf16)(qb.w * qs);
    }

    f32x16 acc, zc;
#pragma unroll
    for (int i = 0; i < 16; ++i) { acc[i] = 0.f; zc[i] = 0.f; }

    const bf16x8* sKv = (const bf16x8*)sK;
    const __bf16* vbase = sVT + (l31 < 8 ? l31 : 8) * 1032;

    // prologue: scores for tile 0 (K garbage in k=8..15 is harmless: B rows are zero there)
    f32x16 st = __builtin_amdgcn_mfma_f32_32x32x16_bf16(sKv[l31], qf, zc, 0, 0, 0);

#pragma unroll 4
    for (int kt = 0; kt < 32; ++kt) {
        // prefetch next K tile early
        bf16x8 kf2 = sKv[((kt + 1) & 31) * 32 + l31];

        // softmax numerators: p = exp2(s * log2e); reg r -> key kb0 + (r&3)+8*(r>>2)+4*hi
        float p[16];
#pragma unroll
        for (int r = 0; r < 16; ++r) p[r] = exp2fast(st[r]);

        // pack to bf16 + exchange halves: c0[g] = keys 8g+4hi'+{0,1}, c1[g] = +{2,3}
        unsigned L0[4], H0[4], L1[4], H1[4];
#pragma unroll
        for (int g = 0; g < 4; ++g) {
            unsigned a0, a1;
            a0 = pack2(p[4 * g + 0], p[4 * g + 1]);
            a1 = pack2(p[4 * g + 2], p[4 * g + 3]);
            plswap(a0, L0[g], H0[g]);
            plswap(a1, L1[g], H1[g]);
        }

        // next tile's QK^T while P is consumed below
        f32x16 st2 = __builtin_amdgcn_mfma_f32_32x32x16_bf16(kf2, qf, zc, 0, 0, 0);

#pragma unroll
        for (int h = 0; h < 2; ++h) {
            int g = 2 * h + hi;
            uint4e pw;
            pw[0] = hi ? L0[2 * h + 1] : L0[2 * h];
            pw[1] = hi ? L1[2 * h + 1] : L1[2 * h];
            pw[2] = hi ? H0[2 * h + 1] : H0[2 * h];
            pw[3] = hi ? H1[2 * h + 1] : H1[2 * h];
            (void)g;
            bf16x8 pf = __builtin_bit_cast(bf16x8, pw);
            bf16x8 vf = *(const bf16x8*)(vbase + kt * 32 + 16 * h + 8 * hi);
            acc = __builtin_amdgcn_mfma_f32_32x32x16_bf16(vf, pf, acc, 0, 0, 0);
        }
        st = st2;
    }

    // acc[4] = row 8 (hi=0) / row 12 (hi=1) of O^T = psum on ALL lanes (ones-row trick)
    float inv = 1.0f / acc[4];
    float4 o;
    o.x = acc[0] * inv; o.y = acc[1] * inv; o.z = acc[2] * inv; o.w = acc[3] * inv;
    *(float4*)(O + (bh * 1024 + qrow) * 8 + 4 * hi) = o;
}

// ---------------------------------------------------------------- out-proj + residual + LN (wave = row)
__global__ __launch_bounds__(256) void proj_ln_kernel(
    float* __restrict__ X, const float* __restrict__ O, const float* __restrict__ Wo,
    const float* __restrict__ gamma, const float* __restrict__ beta, int gi)
{
    __shared__ float sWo[4096];
    __shared__ float so[4][64];
    int tid = threadIdx.x;
    for (int idx = tid; idx < 4096; idx += 256) sWo[idx] = Wo[idx];
    int row0 = blockIdx.x * 4;
    {
        int r = tid >> 6, j = tid & 63;
        int grow = row0 + r;
        int b = grow >> 10, l = grow & 1023;
        so[r][j] = O[((b * 8 + (j >> 3)) * 1024 + l) * 8 + (j & 7)];
    }
    __syncthreads();
    int r = tid >> 6, c = tid & 63;
    float acc = 0.f;
#pragma unroll 8
    for (int j = 0; j < 64; ++j) acc = fmaf(so[r][j], sWo[j * 64 + c], acc);
    float x = X[(row0 + r) * 64 + c] + acc;
    float mean = wave_sum64(x) * (1.0f / 64.0f);
    float dx = x - mean;
    float var = wave_sum64(dx * dx) * (1.0f / 64.0f);
    X[(row0 + r) * 64 + c] = dx * rsqrtf(var + 1e-14f) * gamma[gi] + beta[gi];
}

// ---------------------------------------------------------------- FFN + residual + LN
__global__ __launch_bounds__(256) void ffn_ln_kernel(
    float* __restrict__ X, const float* __restrict__ W1, const float* __restrict__ b1,
    const float* __restrict__ W2, const float* __restrict__ b2,
    const float* __restrict__ gamma, const float* __restrict__ beta, int gi)
{
    __shared__ float sW1[8192];  // [c][j]
    __shared__ float sW2[8192];  // [j][c]
    __shared__ float sX[1024];
    __shared__ float sh[2048];
    int tid = threadIdx.x;
    for (int idx = tid; idx < 8192; idx += 256) { sW1[idx] = W1[idx]; sW2[idx] = W2[idx]; }
    int row0 = blockIdx.x * 16;
    for (int idx = tid; idx < 1024; idx += 256) sX[idx] = X[row0 * 64 + idx];
    __syncthreads();
    for (int idx = tid; idx < 2048; idx += 256) {
        int r = idx >> 7, j = idx & 127;
        float a = b1[j];
#pragma unroll 8
        for (int c = 0; c < 64; ++c) a = fmaf(sX[r * 64 + c], sW1[c * 128 + j], a);
        sh[idx] = fmaxf(a, 0.0f);
    }
    __syncthreads();
#pragma unroll
    for (int iter = 0; iter < 4; ++iter) {
        int idx = iter * 256 + tid;
        int r = idx >> 6, c = idx & 63;
        float a = b2[c];
#pragma unroll 8
        for (int j = 0; j < 128; ++j) a = fmaf(sh[r * 128 + j], sW2[j * 64 + c], a);
        float x = sX[idx] + a;
        float mean = wave_sum64(x) * (1.0f / 64.0f);
        float dx = x - mean;
        float var = wave_sum64(dx * dx) * (1.0f / 64.0f);
        X[row0 * 64 + idx] = dx * rsqrtf(var + 1e-14f) * gamma[gi] + beta[gi];
    }
}

// ---------------------------------------------------------------- pooling attention weights
__global__ __launch_bounds__(256) void aw_kernel(
    const float* __restrict__ X, const float* __restrict__ aW1, const float* __restrict__ ab1,
    const float* __restrict__ aW2, float* __restrict__ aw)
{
    __shared__ float sW[8192];   // aW1 [c][j]
    __shared__ float sX[1024];
    __shared__ float sh[2048];
    int tid = threadIdx.x;
    for (int idx = tid; idx < 8192; idx += 256) sW[idx] = aW1[idx];
    int row0 = blockIdx.x * 16;
    for (int idx = tid; idx < 1024; idx += 256) sX[idx] = X[row0 * 64 + idx];
    __syncthreads();
    for (int idx = tid; idx < 2048; idx += 256) {
        int r = idx >> 7, j = idx & 127;
        float a = ab1[j];
#pragma unroll 8
        for (int c = 0; c < 64; ++c) a = fmaf(sX[r * 64 + c], sW[c * 128 + j], a);
        sh[idx] = tanhf(a) * aW2[j];
    }
    __syncthreads();
    {
        int r = tid >> 4, jj = tid & 15;
        float s = 0.f;
#pragma unroll
        for (int t = 0; t < 8; ++t) s += sh[r * 128 + jj * 8 + t];
#pragma unroll
        for (int off = 8; off > 0; off >>= 1) s += __shfl_xor(s, off, 64);
        if (jj == 0) aw[row0 + r] = s;
    }
}

// ---------------------------------------------------------------- masked pool softmax + final head
__global__ __launch_bounds__(256) void pool_kernel(
    const float* __restrict__ X, const float* __restrict__ aw,
    const float* __restrict__ mask, const float* __restrict__ denc,
    const float* __restrict__ Wout, const float* __restrict__ bout, float* __restrict__ out)
{
    __shared__ float sp[1024];
    __shared__ float red[8];
    __shared__ float sf[4][64];
    int b = blockIdx.x, tid = threadIdx.x;
    float mymax = -INFINITY;
    for (int idx = tid; idx < 1024; idx += 256) {
        float s = (mask[b * 1024 + idx] != 0.0f) ? aw[b * 1024 + idx] : -1e30f;
        sp[idx] = s;
        mymax = fmaxf(mymax, s);
    }
#pragma unroll
    for (int off = 32; off > 0; off >>= 1) mymax = fmaxf(mymax, __shfl_xor(mymax, off, 64));
    if ((tid & 63) == 0) red[tid >> 6] = mymax;
    __syncthreads();
    float gmax = fmaxf(fmaxf(red[0], red[1]), fmaxf(red[2], red[3]));
    float mysum = 0.f;
    for (int idx = tid; idx < 1024; idx += 256) {
        float p = __expf(sp[idx] - gmax);
        sp[idx] = p;
        mysum += p;
    }
    mysum = wave_sum64(mysum);
    if ((tid & 63) == 0) red[4 + (tid >> 6)] = mysum;
    __syncthreads();
    float inv = 1.0f / (red[4] + red[5] + red[6] + red[7]);
    int c = tid & 63, part = tid >> 6;
    float f = 0.f;
    for (int l = part; l < 1024; l += 4) f = fmaf(sp[l], X[(b * 1024 + l) * 64 + c], f);
    sf[part][c] = f;
    __syncthreads();
    if (tid < 64) {
        float fc = (sf[0][tid] + sf[1][tid] + sf[2][tid] + sf[3][tid]) * inv;
        float contrib = fc * Wout[tid] + denc[b * 64 + tid] * Wout[64 + tid];
        contrib = wave_sum64(contrib);
        if (tid == 0) out[b] = 1.0f / (1.0f + __expf(-(contrib + bout[0])));
    }
}

// ---------------------------------------------------------------- launch
extern "C" void kernel_launch(void* const* d_in, const int* in_sizes, int n_in,
                              void* d_out, int out_size, void* d_ws, size_t ws_size,
                              hipStream_t stream)
{
    const float* demo  = (const float*)d_in[0];
    const float* times = (const float*)d_in[1];
    const float* values= (const float*)d_in[2];
    const int*   varis = (const int*)d_in[3];
    const float* emb   = (const float*)d_in[4];
    const float* vW1   = (const float*)d_in[5];
    const float* vb1   = (const float*)d_in[6];
    const float* vW2   = (const float*)d_in[7];
    const float* tW1   = (const float*)d_in[8];
    const float* tb1   = (const float*)d_in[9];
    const float* tW2   = (const float*)d_in[10];
    const float* Wq    = (const float*)d_in[11];
    const float* Wk    = (const float*)d_in[12];
    const float* Wv    = (const float*)d_in[13];
    const float* Wo    = (const float*)d_in[14];
    const float* W1    = (const float*)d_in[15];
    const float* b1    = (const float*)d_in[16];
    const float* W2    = (const float*)d_in[17];
    const float* b2    = (const float*)d_in[18];
    const float* gamma = (const float*)d_in[19];
    const float* beta  = (const float*)d_in[20];
    const float* aW1   = (const float*)d_in[21];
    const float* ab1   = (const float*)d_in[22];
    const float* aW2   = (const float*)d_in[23];
    const float* dW1   = (const float*)d_in[24];
    const float* db1   = (const float*)d_in[25];
    const float* dW2   = (const float*)d_in[26];
    const float* db2   = (const float*)d_in[27];
    const float* Wout  = (const float*)d_in[28];
    const float* bout  = (const float*)d_in[29];
    float* out = (float*)d_out;

    float* ws   = (float*)d_ws;
    float* X    = ws;                  // 1048576 f
    float* mask = X + 1048576;         // 16384 f
    float* qb   = mask + 16384;        // 1048576 f
    float* kb   = qb + 1048576;        // 1048576 f
    float* vb   = kb + 1048576;        // 1048576 f
    float* Ob   = vb + 1048576;        // 1048576 f
    float* awb  = Ob + 1048576;        // 16384 f
    float* denc = awb + 16384;         // 1024 f

    embed_kernel<<<4096, 256, 0, stream>>>(times, values, varis, emb, vW1, vb1, vW2, tW1, tb1, tW2, X, mask);
    demo_kernel<<<16, 128, 0, stream>>>(demo, dW1, db1, dW2, db2, denc);
    for (int i = 0; i < 2; ++i) {
        qkv_kernel<<<1024, 256, 0, stream>>>(X, Wq + i * 4096, Wk + i * 4096, Wv + i * 4096, qb, kb, vb);
        attn_mfma_kernel<<<1024, 256, 0, stream>>>(qb, kb, vb, mask, Ob);
        proj_ln_kernel<<<4096, 256, 0, stream>>>(X, Ob, Wo + i * 4096, gamma, beta, 2 * i);
        ffn_ln_kernel<<<1024, 256, 0, stream>>>(X, W1 + i * 8192, b1 + i * 128, W2 + i * 8192, b2 + i * 64,
                                                gamma, beta, 2 * i + 1);
    }
    aw_kernel<<<1024, 256, 0, stream>>>(X, aW1, ab1, aW2, awb);
    pool_kernel<<<16, 256, 0, stream>>>(X, awb, mask, denc, Wout, bout, out);
}